// Round 9
// baseline (355.801 us; speedup 1.0000x reference)
//
#include <hip/hip_runtime.h>
#include <stdint.h>

#define NNODES 50000
#define NEDGES 400000
#define EMB 128
#define KD 896
#define BM 128

typedef __attribute__((ext_vector_type(8))) short bf16x8;
typedef __attribute__((ext_vector_type(4))) float f32x4;

__device__ __forceinline__ short f2bf(float f) {
  union { float f; uint32_t u; } v; v.f = f;
  uint32_t r = v.u + 0x7FFFu + ((v.u >> 16) & 1u);
  return (short)(r >> 16);
}
__device__ __forceinline__ float bf2f(short s) {
  union { uint32_t u; float f; } v; v.u = ((uint32_t)(uint16_t)s) << 16;
  return v.f;
}
__device__ __forceinline__ float fast_gelu(float x) {
  float x2 = x * x;
  float y = x * (0.7978845608f + 0.03567740814f * x2);
  float e = __expf(2.0f * y);
  float r = __builtin_amdgcn_rcpf(1.0f + e);
  return x - x * r;     // 0.5x(1+tanh(y)); saturates correctly
}

// B layout (validated R2..R7): chunk c = sidx*4 + wn*2 + f, sidx=(i*2+fh)*4+kk
// element: short idx = c*512 + lane*8 + m
// value = W2[(kk*32 + (lane>>4)*8 + m)*896 + i*128 + (wn*4+fh*2+f)*16 + (lane&15)]
__global__ void prep_B(const float* __restrict__ W2, short* __restrict__ Bp) {
  int idx = blockIdx.x * 256 + threadIdx.x;   // 448*256 = 114688 exact
  int m = idx & 7, l = (idx >> 3) & 63, c = idx >> 9;
  int sidx = c >> 2, wn = (c >> 1) & 1, f = c & 1;
  int p = sidx >> 2, kk = sidx & 3, i = p >> 1, fnh = p & 1;
  int o = (wn * 4 + fnh * 2 + f) * 16 + (l & 15);
  int k = kk * 32 + (l >> 4) * 8 + m;
  Bp[idx] = f2bf(W2[k * KD + i * EMB + o]);
}

// W1p: phase-1 A frags (validated R7): idx = (mt*64 + lane)*8 + m; o = mt*16+(lane&15)
__global__ void prep_W1(const float* __restrict__ W1f, const float* __restrict__ b1,
                        short* __restrict__ W1p) {
  int idx = blockIdx.x * 256 + threadIdx.x;   // 16*256 = 4096
  int m = idx & 7, l = (idx >> 3) & 63, mt = idx >> 9;
  int o = mt * 16 + (l & 15), kseg = l >> 4;
  short v = 0;
  if (kseg < 2) {
    if (m < 6) v = f2bf(W1f[m * EMB + o]);
  } else if (kseg == 2) {
    if (m < 6) { float wv = W1f[m * EMB + o]; short hi = f2bf(wv); v = f2bf(wv - bf2f(hi)); }
  } else {
    if (m == 0) v = f2bf(b1[o]);
    else if (m == 1) { float bv = b1[o]; short hi = f2bf(bv); v = f2bf(bv - bf2f(hi)); }
  }
  W1p[idx] = v;
}

// ---- CSR build: histogram -> exclusive scan -> stable-ish scatter ----
__global__ void hist_dst(const int* __restrict__ ei, unsigned* __restrict__ cnt) {
  int e = blockIdx.x * 256 + threadIdx.x;
  if (e < NEDGES) atomicAdd(&cnt[ei[NEDGES + e]], 1u);
}

__global__ __launch_bounds__(1024)
void scan_off(const unsigned* __restrict__ cnt, unsigned* __restrict__ woff) {
  __shared__ unsigned ps[1024];
  const int t = threadIdx.x;
  const int lo = t * 49;
  const int hi = (lo + 49 < NNODES) ? lo + 49 : NNODES;
  unsigned s = 0;
  for (int j = lo; j < hi; ++j) s += cnt[j];
  ps[t] = s;
  __syncthreads();
  for (int d = 1; d < 1024; d <<= 1) {
    unsigned v = (t >= d) ? ps[t - d] : 0u;
    __syncthreads();
    ps[t] += v;
    __syncthreads();
  }
  unsigned run = (t > 0) ? ps[t - 1] : 0u;
  for (int j = lo; j < hi; ++j) { woff[j] = run; run += cnt[j]; }
}

__global__ void scatter_e(const int* __restrict__ ei, unsigned* __restrict__ woff,
                          unsigned* __restrict__ eord) {
  int e = blockIdx.x * 256 + threadIdx.x;
  if (e < NEDGES) {
    unsigned p = atomicAdd(&woff[ei[NEDGES + e]], 1u);
    eord[p] = (unsigned)e;
  }
}

__global__ __launch_bounds__(256, 2)
void nnconv_main(const float* __restrict__ x,
                 const int* __restrict__ ei,
                 const float* __restrict__ ea,
                 const float* __restrict__ b2,
                 const short* __restrict__ Bp,
                 const short* __restrict__ W1p,
                 const unsigned* __restrict__ eord,
                 float* __restrict__ out) {
  // union: phase1/A uses h_s (32KB bf16, swizzled); epilogue uses red_s[128][65] f32
  __shared__ __align__(16) char smem[33280];
  short* h_s = (short*)smem;
  float* red_s = (float*)smem;
  __shared__ __align__(16) float x_t[7][132];
  __shared__ __align__(16) float ea_s[BM * 6];
  __shared__ int dst_s[BM + 4];

  const int t = threadIdx.x;
  const int lane = t & 63;
  const int w = t >> 6;
  const int wm = w >> 1, wn = w & 1;
  const int rowA = lane & 15;
  const int kseg = lane >> 4;
  const int eb = blockIdx.x * BM;
  const char* BpB = (const char*)Bp + wn * 2048 + lane * 16;

  // ---- early B prefetch: chunk (fh=0,i=0) = sidx 0..3 ----
  bf16x8 bcur[4][2];
#pragma unroll
  for (int kk = 0; kk < 4; ++kk)
#pragma unroll
    for (int f = 0; f < 2; ++f)
      bcur[kk][f] = *(const bf16x8*)(BpB + (((size_t)kk * 4 + f) << 10));

  // ---- phase 0: dst-sorted edge gather via eord ----
  if (t < BM) {
    const int e = (int)eord[eb + t];
    const int s = ei[e];
    const int d = ei[NEDGES + e];
    dst_s[t] = d;
#pragma unroll
    for (int i = 0; i < 7; ++i) x_t[i][t] = x[s * 7 + i];
#pragma unroll
    for (int q = 0; q < 6; ++q) ea_s[t * 6 + q] = ea[(size_t)e * 6 + q];
  }
  if (t == BM) dst_s[BM] = -1;    // sentinel
  __syncthreads();

  // ---- phase 1: h = gelu(ea@W1+b1) via MFMA, D[o][edge] into swizzled h_s ----
  {
    bf16x8 wa[8];
#pragma unroll
    for (int mt = 0; mt < 8; ++mt)
      wa[mt] = *(const bf16x8*)(W1p + (mt * 64 + lane) * 8);
#pragma unroll
    for (int et2 = 0; et2 < 2; ++et2) {
      const int e = w * 32 + et2 * 16 + rowA;
      bf16x8 be = (bf16x8){0, 0, 0, 0, 0, 0, 0, 0};
      if (kseg == 3) {
        be[0] = f2bf(1.0f); be[1] = f2bf(1.0f);
      } else {
#pragma unroll
        for (int q = 0; q < 6; ++q) {
          float v = ea_s[e * 6 + q];
          short hi = f2bf(v);
          be[q] = (kseg == 1) ? f2bf(v - bf2f(hi)) : hi;
        }
      }
      const int swz = (e & 15) << 4;
#pragma unroll
      for (int mt = 0; mt < 8; ++mt) {
        f32x4 d = __builtin_amdgcn_mfma_f32_16x16x32_bf16(
            wa[mt], be, (f32x4){0.f, 0.f, 0.f, 0.f}, 0, 0, 0);
        uint32_t h0 = (uint16_t)f2bf(fast_gelu(d[0]));
        uint32_t h1 = (uint16_t)f2bf(fast_gelu(d[1]));
        uint32_t h2 = (uint16_t)f2bf(fast_gelu(d[2]));
        uint32_t h3 = (uint16_t)f2bf(fast_gelu(d[3]));
        uint2 u; u.x = h0 | (h1 << 16); u.y = h2 | (h3 << 16);
        int off = (mt * 32 + kseg * 8) ^ swz;
        *(uint2*)((char*)h_s + e * 256 + off) = u;
      }
    }
  }
  __syncthreads();

  // ---- load A fragments ONCE (i-invariant): 16 frags ----
  bf16x8 A[4][4];
#pragma unroll
  for (int kk = 0; kk < 4; ++kk)
#pragma unroll
    for (int fm = 0; fm < 4; ++fm) {
      int row = wm * 64 + fm * 16 + rowA;
      int off = (kk * 64 + kseg * 16) ^ (rowA << 4);
      A[kk][fm] = *(const bf16x8*)((const char*)h_s + row * 256 + off);
    }

  // ---- K-loop (barrier-free) + segmented-reduction epilogue, per fh half ----
#pragma unroll
  for (int fh = 0; fh < 2; ++fh) {
    f32x4 acc2[4][2];
#pragma unroll
    for (int a = 0; a < 4; ++a) {
      acc2[a][0] = (f32x4){0.f, 0.f, 0.f, 0.f};
      acc2[a][1] = (f32x4){0.f, 0.f, 0.f, 0.f};
    }
#pragma unroll 1
    for (int i = 0; i < 7; ++i) {
      float b2v0 = b2[i * EMB + wn * 64 + fh * 32 + rowA];
      float b2v1 = b2[i * EMB + wn * 64 + fh * 32 + 16 + rowA];
      int nsidx;
      if (fh == 0) nsidx = (i < 6) ? (i + 1) * 8 : 4;
      else         nsidx = (i < 6) ? (i + 1) * 8 + 4 : 52;

      f32x4 tmp[4][2];
      const f32x4 zz = (f32x4){0.f, 0.f, 0.f, 0.f};
#pragma unroll
      for (int fm = 0; fm < 4; ++fm) {
        tmp[fm][0] = __builtin_amdgcn_mfma_f32_16x16x32_bf16(A[0][fm], bcur[0][0], zz, 0, 0, 0);
        tmp[fm][1] = __builtin_amdgcn_mfma_f32_16x16x32_bf16(A[0][fm], bcur[0][1], zz, 0, 0, 0);
      }
      bcur[0][0] = *(const bf16x8*)(BpB + (((size_t)(nsidx + 0) * 4 + 0) << 10));
      bcur[0][1] = *(const bf16x8*)(BpB + (((size_t)(nsidx + 0) * 4 + 1) << 10));
#pragma unroll
      for (int kk = 1; kk < 4; ++kk) {
#pragma unroll
        for (int fm = 0; fm < 4; ++fm) {
          tmp[fm][0] = __builtin_amdgcn_mfma_f32_16x16x32_bf16(A[kk][fm], bcur[kk][0], tmp[fm][0], 0, 0, 0);
          tmp[fm][1] = __builtin_amdgcn_mfma_f32_16x16x32_bf16(A[kk][fm], bcur[kk][1], tmp[fm][1], 0, 0, 0);
        }
        bcur[kk][0] = *(const bf16x8*)(BpB + (((size_t)(nsidx + kk) * 4 + 0) << 10));
        bcur[kk][1] = *(const bf16x8*)(BpB + (((size_t)(nsidx + kk) * 4 + 1) << 10));
      }
#pragma unroll
      for (int fm = 0; fm < 4; ++fm) {
        f32x4 xv = *(const f32x4*)&x_t[i][wm * 64 + fm * 16 + kseg * 4];
#pragma unroll
        for (int r = 0; r < 4; ++r) {
          acc2[fm][0][r] += xv[r] * (tmp[fm][0][r] + b2v0);
          acc2[fm][1][r] += xv[r] * (tmp[fm][1][r] + b2v1);
        }
      }
    }

    // ---- epilogue: acc -> LDS, wave-uniform segmented scan over sorted dst ----
    __syncthreads();            // h_s/red_s reuse + prior scan completion
#pragma unroll
    for (int fm = 0; fm < 4; ++fm)
#pragma unroll
      for (int r = 0; r < 4; ++r) {
        const int row = wm * 64 + fm * 16 + kseg * 4 + r;
        red_s[row * 65 + wn * 32 + rowA]      = acc2[fm][0][r];
        red_s[row * 65 + wn * 32 + 16 + rowA] = acc2[fm][1][r];
      }
    __syncthreads();
    {
      const int gcol = fh * 32 + (lane & 31) + (lane >> 5) * 64;
      const int base = w * 32;
      float run = 0.f;
      int runstart = 0;
      for (int j = 0; j < 32; ++j) {
        run += red_s[(base + j) * 65 + lane];
        const int d = dst_s[base + j];
        const bool endrun = (j == 31) || (dst_s[base + j + 1] != d);
        if (endrun) {                       // wave-uniform branch (d from LDS broadcast)
          float* op = out + (size_t)d * EMB + gcol;
          if (runstart > 0 && j < 31) *op = run;   // interior run: exclusive writer
          else atomicAdd(op, run);                 // block/chunk-boundary run
          run = 0.f;
          runstart = j + 1;
        }
      }
    }
  }
}

// out = out/clip(cnt,1) + x@root + bias
__global__ void finalize(const float* __restrict__ x, const float* __restrict__ root,
                         const float* __restrict__ bias, const unsigned* __restrict__ cnt,
                         float* __restrict__ out) {
  int idx = blockIdx.x * 256 + threadIdx.x;
  int n = idx >> 7, o = idx & 127;
  float c = fmaxf((float)cnt[n], 1.0f);
  float v = out[idx] / c + bias[o];
#pragma unroll
  for (int i = 0; i < 7; ++i) v += x[n * 7 + i] * root[i * EMB + o];
  out[idx] = v;
}

extern "C" void kernel_launch(void* const* d_in, const int* in_sizes, int n_in,
                              void* d_out, int out_size, void* d_ws, size_t ws_size,
                              hipStream_t stream) {
  const float* x    = (const float*)d_in[0];
  const int*   ei   = (const int*)d_in[1];
  const float* ea   = (const float*)d_in[2];
  const float* W1   = (const float*)d_in[3];
  const float* b1   = (const float*)d_in[4];
  const float* W2   = (const float*)d_in[5];
  const float* b2   = (const float*)d_in[6];
  const float* root = (const float*)d_in[7];
  const float* bias = (const float*)d_in[8];
  float* out = (float*)d_out;

  short*    Bp    = (short*)d_ws;                               // 229376 B
  short*    W1p   = (short*)((char*)d_ws + 229376);             // 8192 B
  unsigned* cnt_u = (unsigned*)((char*)d_ws + 237568);          // 200000 B
  unsigned* woff  = (unsigned*)((char*)d_ws + 437568);          // 200000 B
  unsigned* eord  = (unsigned*)((char*)d_ws + 637568);          // 1600000 B

  hipMemsetAsync(out, 0, (size_t)NNODES * EMB * sizeof(float), stream);
  hipMemsetAsync(cnt_u, 0, (size_t)NNODES * sizeof(unsigned), stream);
  prep_B<<<448, 256, 0, stream>>>(W2, Bp);
  prep_W1<<<16, 256, 0, stream>>>(W1, b1, W1p);
  hist_dst<<<(NEDGES + 255) / 256, 256, 0, stream>>>(ei, cnt_u);
  scan_off<<<1, 1024, 0, stream>>>(cnt_u, woff);
  scatter_e<<<(NEDGES + 255) / 256, 256, 0, stream>>>(ei, woff, eord);
  nnconv_main<<<NEDGES / BM, 256, 0, stream>>>(x, ei, ea, b2, Bp, W1p, eord, out);
  finalize<<<NNODES * EMB / 256, 256, 0, stream>>>(x, root, bias, cnt_u, out);
}